// Round 1
// 275.376 us; speedup vs baseline: 1.0185x; 1.0185x over previous
//
#include <hip/hip_runtime.h>

#define Bsz  4
#define Tseq 2048
#define Cdim 512
#define Hn   8
#define Dh   64
#define BT   8192     // Bsz*Tseq tokens
#define NQKV 1536
#define NEG_BIG (-1e30f)

typedef __attribute__((ext_vector_type(8))) short bf16x8;  // 8 bf16 = 4 VGPRs
typedef __attribute__((ext_vector_type(4))) short bf16x4;  // 4 bf16 = 2 VGPRs
typedef __attribute__((ext_vector_type(4))) float f32x4;

__device__ __forceinline__ float b2f(short s) {
    unsigned u = ((unsigned)(unsigned short)s) << 16;
    float f; __builtin_memcpy(&f, &u, 4); return f;
}
__device__ __forceinline__ short f2b(float f) {
    unsigned u; __builtin_memcpy(&u, &f, 4);
    u = (u + 0x7fffu + ((u >> 16) & 1u)) >> 16;   // RNE
    return (short)u;
}
// async global->LDS, 16B/lane; LDS dest = wave-uniform base + lane*16
__device__ __forceinline__ void g2l16(const short* g, short* l) {
    __builtin_amdgcn_global_load_lds(
        (const __attribute__((address_space(1))) unsigned int*)(uintptr_t)g,
        (__attribute__((address_space(3))) unsigned int*)l, 16, 0, 0);
}

// ---------------- prep: fused weight transpose (blocks 0..255) + LayerNorm1 (blocks 256..2303) ----------------
__global__ __launch_bounds__(256) void k_prep(const float* __restrict__ wq, const float* __restrict__ wk,
                                              const float* __restrict__ wv, const float* __restrict__ wff,
                                              short* __restrict__ wqkvt, short* __restrict__ wfft,
                                              const float* __restrict__ x, const float* __restrict__ g,
                                              const float* __restrict__ b, short* __restrict__ out) {
    const int blk = blockIdx.x, tid = threadIdx.x;
    if (blk < 256) {
        __shared__ float ldsT[64 * 65];          // 64x64 tile, pad 65: conflict-free both phases
        if (blk < 192) {                         // QKV heads: per-head 512x64 -> 64x512
            int hm = blk >> 3, ct = blk & 7;
            int proj = hm >> 3, h = hm & 7;
            const float* w = (proj == 0) ? wq : (proj == 1 ? wk : wv);
#pragma unroll
            for (int i = 0; i < 16; i++) {
                int flat = i * 256 + tid, cc = flat >> 6, dd = flat & 63;
                ldsT[dd * 65 + cc] = w[(h * 512 + ct * 64 + cc) * 64 + dd];   // coalesced in dd
            }
            __syncthreads();
#pragma unroll
            for (int i = 0; i < 16; i++) {
                int flat = i * 256 + tid, dd = flat >> 6, cc = flat & 63;
                int n = proj * 512 + h * 64 + dd;
                wqkvt[n * 512 + ct * 64 + cc] = f2b(ldsT[dd * 65 + cc]);      // coalesced in cc
            }
        } else {                                 // FF: 512x512 -> 512x512 transposed
            int b2 = blk - 192, rt = b2 >> 3, nt8 = b2 & 7;
#pragma unroll
            for (int i = 0; i < 16; i++) {
                int flat = i * 256 + tid, cc = flat >> 6, nn = flat & 63;
                ldsT[nn * 65 + cc] = wff[(rt * 64 + cc) * 512 + nt8 * 64 + nn];
            }
            __syncthreads();
#pragma unroll
            for (int i = 0; i < 16; i++) {
                int flat = i * 256 + tid, nn = flat >> 6, cc = flat & 63;
                wfft[(nt8 * 64 + nn) * 512 + rt * 64 + cc] = f2b(ldsT[nn * 65 + cc]);
            }
        }
    } else {                                     // LayerNorm1: one wave per token row
        int row  = (blk - 256) * 4 + (tid >> 6);
        int lane = tid & 63;
        const f32x4 a0 = *(const f32x4*)(x + row * Cdim + lane * 8);
        const f32x4 a1 = *(const f32x4*)(x + row * Cdim + lane * 8 + 4);
        float v[8] = {a0[0], a0[1], a0[2], a0[3], a1[0], a1[1], a1[2], a1[3]};
        float s = 0.f, sq = 0.f;
#pragma unroll
        for (int i = 0; i < 8; i++) { s += v[i]; sq += v[i] * v[i]; }
#pragma unroll
        for (int off = 1; off < 64; off <<= 1) { s += __shfl_xor(s, off); sq += __shfl_xor(sq, off); }
        float mean = s * (1.f / 512.f);
        float var  = sq * (1.f / 512.f) - mean * mean;
        float rstd = rsqrtf(var + 1e-5f);
        const f32x4 g0 = *(const f32x4*)(g + lane * 8);
        const f32x4 g1 = *(const f32x4*)(g + lane * 8 + 4);
        const f32x4 b0 = *(const f32x4*)(b + lane * 8);
        const f32x4 b1 = *(const f32x4*)(b + lane * 8 + 4);
        float gg[8] = {g0[0], g0[1], g0[2], g0[3], g1[0], g1[1], g1[2], g1[3]};
        float bb[8] = {b0[0], b0[1], b0[2], b0[3], b1[0], b1[1], b1[2], b1[3]};
        bf16x8 o;
#pragma unroll
        for (int i = 0; i < 8; i++) o[i] = f2b((v[i] - mean) * rstd * gg[i] + bb[i]);
        *(bf16x8*)(out + row * Cdim + lane * 8) = o;
    }
}

// ---------------- LayerNorm (standalone, for LN2): fp32 in, bf16 out ----------------
__global__ __launch_bounds__(256) void k_ln(const float* __restrict__ x, const float* __restrict__ g,
                                            const float* __restrict__ b, short* __restrict__ out) {
    int row  = blockIdx.x * 4 + (threadIdx.x >> 6);
    int lane = threadIdx.x & 63;
    const f32x4 a0 = *(const f32x4*)(x + row * Cdim + lane * 8);
    const f32x4 a1 = *(const f32x4*)(x + row * Cdim + lane * 8 + 4);
    float v[8] = {a0[0], a0[1], a0[2], a0[3], a1[0], a1[1], a1[2], a1[3]};
    float s = 0.f, sq = 0.f;
#pragma unroll
    for (int i = 0; i < 8; i++) { s += v[i]; sq += v[i] * v[i]; }
#pragma unroll
    for (int off = 1; off < 64; off <<= 1) { s += __shfl_xor(s, off); sq += __shfl_xor(sq, off); }
    float mean = s * (1.f / 512.f);
    float var  = sq * (1.f / 512.f) - mean * mean;
    float rstd = rsqrtf(var + 1e-5f);
    const f32x4 g0 = *(const f32x4*)(g + lane * 8);
    const f32x4 g1 = *(const f32x4*)(g + lane * 8 + 4);
    const f32x4 b0 = *(const f32x4*)(b + lane * 8);
    const f32x4 b1 = *(const f32x4*)(b + lane * 8 + 4);
    float gg[8] = {g0[0], g0[1], g0[2], g0[3], g1[0], g1[1], g1[2], g1[3]};
    float bb[8] = {b0[0], b0[1], b0[2], b0[3], b1[0], b1[1], b1[2], b1[3]};
    bf16x8 o;
#pragma unroll
    for (int i = 0; i < 8; i++) o[i] = f2b((v[i] - mean) * rstd * gg[i] + bb[i]);
    *(bf16x8*)(out + row * Cdim + lane * 8) = o;
}

// ---------------- QKV GEMM v2: 128x128 block tile, LDS-staged via global_load_lds ----------------
__global__ __launch_bounds__(256) void k_gemm_qkv(const short* __restrict__ A, const short* __restrict__ Wt,
                                                  short* __restrict__ q, short* __restrict__ k,
                                                  short* __restrict__ vt) {
    const int tid = threadIdx.x;
    const int wave = tid >> 6, lane = tid & 63;
    const int quad = lane >> 4, l15 = lane & 15;
    const int m0 = blockIdx.x * 128, n0 = blockIdx.y * 128;
    const int wm = wave & 1, wn = wave >> 1;
    __shared__ __align__(16) short As[128 * 32];   // [row][k] 64B rows
    __shared__ __align__(16) short Bs[128 * 32];
    f32x4 acc[4][4];
#pragma unroll
    for (int i = 0; i < 4; i++)
#pragma unroll
        for (int j = 0; j < 4; j++) acc[i][j] = (f32x4){0.f, 0.f, 0.f, 0.f};
    const int lr = lane >> 2, lc = lane & 3;       // staging: row = lane/4, 16B-col = lane%4
    const short* Ag = A  + (m0 + wave * 32 + lr) * Cdim + lc * 8;
    const short* Bg = Wt + (n0 + wave * 32 + lr) * Cdim + lc * 8;
    short* Al = As + wave * 1024;                  // wave-uniform LDS dest (shorts)
    short* Bl = Bs + wave * 1024;
    for (int kk = 0; kk < 16; kk++) {
        const int k0 = kk * 32;
        g2l16(Ag + k0,             Al);
        g2l16(Ag + 16 * Cdim + k0, Al + 512);
        g2l16(Bg + k0,             Bl);
        g2l16(Bg + 16 * Cdim + k0, Bl + 512);
        __syncthreads();                           // drains vmcnt before reads
        bf16x8 a[4], w[4];
#pragma unroll
        for (int mt = 0; mt < 4; mt++) a[mt] = *(const bf16x8*)(As + (wm * 64 + mt * 16 + l15) * 32 + quad * 8);
#pragma unroll
        for (int nt = 0; nt < 4; nt++) w[nt] = *(const bf16x8*)(Bs + (wn * 64 + nt * 16 + l15) * 32 + quad * 8);
#pragma unroll
        for (int mt = 0; mt < 4; mt++)
#pragma unroll
            for (int nt = 0; nt < 4; nt++)
                acc[mt][nt] = __builtin_amdgcn_mfma_f32_16x16x32_bf16(a[mt], w[nt], acc[mt][nt], 0, 0, 0);
        __syncthreads();                           // protect tiles before next staging
    }
    // epilogue: proj block-uniform (128 | 512), head wave-uniform (n0w 64-aligned)
    const int proj = n0 >> 9;
    const int n0w  = n0 + wn * 64;
    const int hh   = (n0w & 511) >> 6;
    const int m0w  = m0 + wm * 64;
#pragma unroll
    for (int mt = 0; mt < 4; mt++) {
#pragma unroll
        for (int r = 0; r < 4; r++) {
            int t  = m0w + mt * 16 + quad * 4 + r;
            int bi = t >> 11, tt = t & 2047;
#pragma unroll
            for (int nt = 0; nt < 4; nt++) {
                int d = nt * 16 + l15;
                short val = f2b(acc[mt][nt][r]);
                if (proj == 0)      q [((bi * Hn + hh) * Tseq + tt) * Dh + d] = val;
                else if (proj == 1) k [((bi * Hn + hh) * Tseq + tt) * Dh + d] = val;
                else                vt[((bi * Hn + hh) * Dh + d) * Tseq + tt] = val;
            }
        }
    }
}

// ---------------- causal flash attention v10 ----------------
// Round-12 theory: counters (Mfma 4.5%, VALU 21%, occ 27%) say latency-bound + block-starved
// tail. Three fixes, all targeting exposed latency:
//  (1) LPT dispatch: qtile descends with linear block id -> longest blocks first, no tail.
//  (2) bh->XCD affinity: XCD (D&7) only touches bh 4x..4x+3 -> K/V 2MB < 4MB XCD L2.
//  (3) pipeline: V loads issued BEFORE softmax (hidden under ~1.2k cy of VALU); K
//      double-buffered across iterations (static ping-pong names; no runtime indexing).
#define ATTN_STEP(KC, KN)                                                                   \
    do {                                                                                    \
        const int s0 = kt * 64;                                                             \
        bf16x8 vr[2][4];                                                                    \
        _Pragma("unroll")                                                                   \
        for (int c = 0; c < 2; c++)                                                         \
            _Pragma("unroll")                                                               \
            for (int v4 = 0; v4 < 4; v4++)                                                  \
                vr[c][v4] = *(const bf16x8*)(V + (v4 * 16 + l15) * Tseq + s0 + c * 32 + quad * 8); \
        const int s0n = (kt + 4 < nkt) ? (kt + 4) * 64 : s0;                                \
        _Pragma("unroll")                                                                   \
        for (int nt = 0; nt < 4; nt++) {                                                    \
            KN[0][nt] = *(const bf16x8*)(K + (s0n + nt * 16 + l15) * Dh + quad * 8);        \
            KN[1][nt] = *(const bf16x8*)(K + (s0n + nt * 16 + l15) * Dh + 32 + quad * 8);   \
        }                                                                                   \
        f32x4 st[4];                                                                        \
        _Pragma("unroll")                                                                   \
        for (int nt = 0; nt < 4; nt++) {                                                    \
            f32x4 z = (f32x4){0.f, 0.f, 0.f, 0.f};                                          \
            z = __builtin_amdgcn_mfma_f32_16x16x32_bf16(KC[0][nt], qa[0], z, 0, 0, 0);      \
            z = __builtin_amdgcn_mfma_f32_16x16x32_bf16(KC[1][nt], qa[1], z, 0, 0, 0);      \
            st[nt] = z;                                                                     \
        }                                                                                   \
        __builtin_amdgcn_sched_barrier(0); /* pin V+Knext issue above the softmax */        \
        const int qq = q0 + l15;                                                            \
        if (s0 + 63 > q0) {                                                                 \
            _Pragma("unroll")                                                               \
            for (int nt = 0; nt < 4; nt++)                                                  \
                _Pragma("unroll")                                                           \
                for (int r = 0; r < 4; r++) {                                               \
                    int s = s0 + nt * 16 + quad * 4 + r;                                    \
                    st[nt][r] = (s > qq) ? NEG_BIG : st[nt][r] * sc;                        \
                }                                                                           \
        } else {                                                                            \
            _Pragma("unroll")                                                               \
            for (int nt = 0; nt < 4; nt++)                                                  \
                _Pragma("unroll")                                                           \
                for (int r = 0; r < 4; r++) st[nt][r] *= sc;                                \
        }                                                                                   \
        float mx = fmaxf(fmaxf(fmaxf(st[0][0], st[0][1]), fmaxf(st[0][2], st[0][3])),       \
                         fmaxf(fmaxf(st[1][0], st[1][1]), fmaxf(st[1][2], st[1][3])));      \
        mx = fmaxf(mx, fmaxf(fmaxf(fmaxf(st[2][0], st[2][1]), fmaxf(st[2][2], st[2][3])),   \
                             fmaxf(fmaxf(st[3][0], st[3][1]), fmaxf(st[3][2], st[3][3])))); \
        mx = fmaxf(mx, __shfl_xor(mx, 16));                                                 \
        mx = fmaxf(mx, __shfl_xor(mx, 32));                                                 \
        float mn    = fmaxf(m_i, mx);                                                       \
        float alpha = __builtin_amdgcn_exp2f(m_i - mn);                                     \
        m_i = mn;                                                                           \
        float rs = 0.f;                                                                     \
        bf16x4 pk[4];                                                                       \
        _Pragma("unroll")                                                                   \
        for (int nt = 0; nt < 4; nt++) {                                                    \
            _Pragma("unroll")                                                               \
            for (int r = 0; r < 4; r++) {                                                   \
                float p = __builtin_amdgcn_exp2f(st[nt][r] - mn);                           \
                rs += p;                                                                    \
                pk[nt][r] = f2b(p);                                                         \
            }                                                                               \
        }                                                                                   \
        rs += __shfl_xor(rs, 16);                                                           \
        rs += __shfl_xor(rs, 32);                                                           \
        l_i = l_i * alpha + rs;                                                             \
        _Pragma("unroll")                                                                   \
        for (int nt = 0; nt < 4; nt++)                                                      \
            *(bf16x4*)(pw + l15 * 72 + nt * 16 + quad * 4) = pk[nt];                        \
        _Pragma("unroll")                                                                   \
        for (int r = 0; r < 4; r++) {                                                       \
            float ar = __shfl(alpha, quad * 4 + r);                                         \
            _Pragma("unroll")                                                               \
            for (int dt = 0; dt < 4; dt++) o[dt][r] *= ar;                                  \
        }                                                                                   \
        asm volatile("s_waitcnt lgkmcnt(0)" ::: "memory");                                  \
        bf16x8 pa[2];                                                                       \
        _Pragma("unroll")                                                                   \
        for (int c = 0; c < 2; c++)                                                         \
            pa[c] = *(const bf16x8*)(pw + l15 * 72 + c * 32 + quad * 8);                    \
        _Pragma("unroll")                                                                   \
        for (int c = 0; c < 2; c++)                                                         \
            _Pragma("unroll")                                                               \
            for (int v4 = 0; v4 < 4; v4++)                                                  \
                o[v4] = __builtin_amdgcn_mfma_f32_16x16x32_bf16(pa[c], vr[c][v4], o[v4], 0, 0, 0); \
    } while (0)

__global__ __launch_bounds__(256) void k_attn(const short* __restrict__ qb, const short* __restrict__ kb,
                                              const short* __restrict__ vtb, const float* __restrict__ x,
                                              float* __restrict__ out1) {
    const int wave = threadIdx.x >> 6, lane = threadIdx.x & 63;
    const int quad = lane >> 4, l15 = lane & 15;
    // Linear dispatch id D = by*gridDim.x + bx; blocks dispatch in D order, round-robin XCDs.
    // qtile = 127 - D/32: longest blocks (qtile 127) dispatch first (LPT packing).
    // bh = (D&7)*4 + ((D>>3)&3): per qtile-group, XCD x gets bh in {4x..4x+3} only.
    const int D  = blockIdx.y * 128 + blockIdx.x;
    const int j5 = D & 31;
    const int bh = (j5 & 7) * 4 + (j5 >> 3);
    const int qtile = 127 - (D >> 5);
    const int q0 = qtile * 16;
    const short* Q = qb  + bh * Tseq * Dh;
    const short* K = kb  + bh * Tseq * Dh;
    const short* V = vtb + bh * Dh * Tseq;      // [d][s]

    __shared__ __align__(16) float ldsO[4][16][64];   // combine zones; P tiles overlay in-loop
    __shared__ float ldsM[4][16];
    __shared__ float ldsL[4][16];
    short* pw = (short*)&ldsO[0][0][0] + wave * (16 * 72);  // 16x64 P tile, stride 72

    bf16x8 qa[2];
#pragma unroll
    for (int c = 0; c < 2; c++)
        qa[c] = *(const bf16x8*)(Q + (q0 + l15) * Dh + c * 32 + quad * 8);

    f32x4 o[4];
#pragma unroll
    for (int i = 0; i < 4; i++) o[i] = (f32x4){0.f, 0.f, 0.f, 0.f};
    float m_i = NEG_BIG, l_i = 0.f;             // per-lane: this lane's q = q0 + l15

    const float sc = 0.125f * 1.44269504089f;   // scale * log2(e): softmax in exp2 domain
    const int nkt = (q0 + 79) >> 6;             // 64-key tiles covering keys <= q0+15
    int kt = wave;                              // strided split-K across the 4 waves
    if (kt < nkt) {
        bf16x8 kb0[2][4], kb1[2][4];            // K double buffers (static names only)
#pragma unroll
        for (int nt = 0; nt < 4; nt++) {
            kb0[0][nt] = *(const bf16x8*)(K + (kt * 64 + nt * 16 + l15) * Dh + quad * 8);
            kb0[1][nt] = *(const bf16x8*)(K + (kt * 64 + nt * 16 + l15) * Dh + 32 + quad * 8);
        }
        while (true) {
            ATTN_STEP(kb0, kb1);
            kt += 4; if (kt >= nkt) break;
            ATTN_STEP(kb1, kb0);
            kt += 4; if (kt >= nkt) break;
        }
    }
    // ---- flash-combine of the 4 wave partials (m,l per-lane at q=l15) ----
    if (quad == 0) ldsM[wave][l15] = m_i;
    __syncthreads();
    float Ml = fmaxf(fmaxf(ldsM[0][l15], ldsM[1][l15]), fmaxf(ldsM[2][l15], ldsM[3][l15]));
    float swl = __builtin_amdgcn_exp2f(m_i - Ml);            // empty wave: exp2(-1e30-M)=0
    l_i *= swl;
    if (quad == 0) ldsL[wave][l15] = l_i;
#pragma unroll
    for (int r = 0; r < 4; r++) {
        int row = quad * 4 + r;
        float Mr  = fmaxf(fmaxf(ldsM[0][row], ldsM[1][row]), fmaxf(ldsM[2][row], ldsM[3][row]));
        float swr = __builtin_amdgcn_exp2f(ldsM[wave][row] - Mr);
#pragma unroll
        for (int v4 = 0; v4 < 4; v4++)
            ldsO[wave][row][v4 * 16 + l15] = o[v4][r] * swr;
    }
    __syncthreads();
    const int bi = bh >> 3, hh = bh & 7;
#pragma unroll
    for (int j = 0; j < 4; j++) {
        int row = wave * 4 + j;
        float L  = ldsL[0][row] + ldsL[1][row] + ldsL[2][row] + ldsL[3][row];
        float Of = ldsO[0][row][lane] + ldsO[1][row][lane] + ldsO[2][row][lane] + ldsO[3][row][lane];
        int t   = q0 + row;
        int idx = (bi * Tseq + t) * Cdim + hh * Dh + lane;
        out1[idx] = x[idx] + Of / L;
    }
}

// ---------------- FF GEMM v2: 128x128 LDS-staged, fused bias+ReLU+residual, fp32 out ----------------
__global__ __launch_bounds__(256) void k_gemm_ff(const short* __restrict__ A, const short* __restrict__ Wt,
                                                 const float* __restrict__ bias, const float* __restrict__ res,
                                                 float* __restrict__ out) {
    const int tid = threadIdx.x;
    const int wave = tid >> 6, lane = tid & 63;
    const int quad = lane >> 4, l15 = lane & 15;
    const int m0 = blockIdx.x * 128, n0 = blockIdx.y * 128;
    const int wm = wave & 1, wn = wave >> 1;
    __shared__ __align__(16) short As[128 * 32];
    __shared__ __align__(16) short Bs[128 * 32];
    f32x4 acc[4][4];
#pragma unroll
    for (int i = 0; i < 4; i++)
#pragma unroll
        for (int j = 0; j < 4; j++) acc[i][j] = (f32x4){0.f, 0.f, 0.f, 0.f};
    const int lr = lane >> 2, lc = lane & 3;
    const short* Ag = A  + (m0 + wave * 32 + lr) * Cdim + lc * 8;
    const short* Bg = Wt + (n0 + wave * 32 + lr) * Cdim + lc * 8;
    short* Al = As + wave * 1024;
    short* Bl = Bs + wave * 1024;
    for (int kk = 0; kk < 16; kk++) {
        const int k0 = kk * 32;
        g2l16(Ag + k0,             Al);
        g2l16(Ag + 16 * Cdim + k0, Al + 512);
        g2l16(Bg + k0,             Bl);
        g2l16(Bg + 16 * Cdim + k0, Bl + 512);
        __syncthreads();
        bf16x8 a[4], w[4];
#pragma unroll
        for (int mt = 0; mt < 4; mt++) a[mt] = *(const bf16x8*)(As + (wm * 64 + mt * 16 + l15) * 32 + quad * 8);
#pragma unroll
        for (int nt = 0; nt < 4; nt++) w[nt] = *(const bf16x8*)(Bs + (wn * 64 + nt * 16 + l15) * 32 + quad * 8);
#pragma unroll
        for (int mt = 0; mt < 4; mt++)
#pragma unroll
            for (int nt = 0; nt < 4; nt++)
                acc[mt][nt] = __builtin_amdgcn_mfma_f32_16x16x32_bf16(a[mt], w[nt], acc[mt][nt], 0, 0, 0);
        __syncthreads();
    }
    const int m0w = m0 + wm * 64, n0w = n0 + wn * 64;
#pragma unroll
    for (int mt = 0; mt < 4; mt++) {
#pragma unroll
        for (int r = 0; r < 4; r++) {
            int t = m0w + mt * 16 + quad * 4 + r;
#pragma unroll
            for (int nt = 0; nt < 4; nt++) {
                int n = n0w + nt * 16 + l15;
                float fv = acc[mt][nt][r] + bias[n];
                fv = fmaxf(fv, 0.f);
                out[t * Cdim + n] = res[t * Cdim + n] + fv;
            }
        }
    }
}

extern "C" void kernel_launch(void* const* d_in, const int* in_sizes, int n_in,
                              void* d_out, int out_size, void* d_ws, size_t ws_size,
                              hipStream_t stream) {
    const float* x   = (const float*)d_in[0];
    const float* wq  = (const float*)d_in[1];
    const float* wk  = (const float*)d_in[2];
    const float* wv  = (const float*)d_in[3];
    const float* wff = (const float*)d_in[4];
    const float* bff = (const float*)d_in[5];
    const float* g1  = (const float*)d_in[6];
    const float* b1  = (const float*)d_in[7];
    const float* g2  = (const float*)d_in[8];
    const float* b2  = (const float*)d_in[9];

    char* p = (char*)d_ws;                                  // ~50 MB total scratch
    short* wqkvt = (short*)p; p += (size_t)NQKV * Cdim * 2;
    short* wfft  = (short*)p; p += (size_t)Cdim * Cdim * 2;
    short* h1    = (short*)p; p += (size_t)BT * Cdim * 2;   // reused as h2 after attention
    short* qb    = (short*)p; p += (size_t)BT * Cdim * 2;
    short* kb    = (short*)p; p += (size_t)BT * Cdim * 2;
    short* vtb   = (short*)p; p += (size_t)BT * Cdim * 2;
    float* out1  = (float*)p; p += (size_t)BT * Cdim * 4;

    hipLaunchKernelGGL(k_prep,     dim3(2304),    dim3(256), 0, stream,
                       wq, wk, wv, wff, wqkvt, wfft, x, g1, b1, h1);
    hipLaunchKernelGGL(k_gemm_qkv, dim3(64, 12),  dim3(256), 0, stream, h1, wqkvt, qb, kb, vtb);
    hipLaunchKernelGGL(k_attn,     dim3(128, 32), dim3(256), 0, stream, qb, kb, vtb, x, out1);
    hipLaunchKernelGGL(k_ln,       dim3(2048),    dim3(256), 0, stream, out1, g2, b2, h1);
    hipLaunchKernelGGL(k_gemm_ff,  dim3(64, 4),   dim3(256), 0, stream, h1, wfft, bff, out1, (float*)d_out);
}

// Round 2
// 180.680 us; speedup vs baseline: 1.5524x; 1.5241x over previous
//
#include <hip/hip_runtime.h>

#define Bsz  4
#define Tseq 2048
#define Cdim 512
#define Hn   8
#define Dh   64
#define BT   8192     // Bsz*Tseq tokens
#define NQKV 1536
#define NEG_BIG (-1e30f)

typedef __attribute__((ext_vector_type(8))) short bf16x8;  // 8 bf16 = 4 VGPRs
typedef __attribute__((ext_vector_type(4))) short bf16x4;  // 4 bf16 = 2 VGPRs
typedef __attribute__((ext_vector_type(4))) float f32x4;

__device__ __forceinline__ float b2f(short s) {
    unsigned u = ((unsigned)(unsigned short)s) << 16;
    float f; __builtin_memcpy(&f, &u, 4); return f;
}
__device__ __forceinline__ short f2b(float f) {
    unsigned u; __builtin_memcpy(&u, &f, 4);
    u = (u + 0x7fffu + ((u >> 16) & 1u)) >> 16;   // RNE
    return (short)u;
}
// async global->LDS, 16B/lane; LDS dest = wave-uniform base + lane*16
__device__ __forceinline__ void g2l16(const short* g, short* l) {
    __builtin_amdgcn_global_load_lds(
        (const __attribute__((address_space(1))) unsigned int*)(uintptr_t)g,
        (__attribute__((address_space(3))) unsigned int*)l, 16, 0, 0);
}

// ---------------- prep: fused weight transpose (blocks 0..255) + LayerNorm1 (blocks 256..2303) ----------------
__global__ __launch_bounds__(256) void k_prep(const float* __restrict__ wq, const float* __restrict__ wk,
                                              const float* __restrict__ wv, const float* __restrict__ wff,
                                              short* __restrict__ wqkvt, short* __restrict__ wfft,
                                              const float* __restrict__ x, const float* __restrict__ g,
                                              const float* __restrict__ b, short* __restrict__ out) {
    const int blk = blockIdx.x, tid = threadIdx.x;
    if (blk < 256) {
        __shared__ float ldsT[64 * 65];          // 64x64 tile, pad 65: conflict-free both phases
        if (blk < 192) {                         // QKV heads: per-head 512x64 -> 64x512
            int hm = blk >> 3, ct = blk & 7;
            int proj = hm >> 3, h = hm & 7;
            const float* w = (proj == 0) ? wq : (proj == 1 ? wk : wv);
#pragma unroll
            for (int i = 0; i < 16; i++) {
                int flat = i * 256 + tid, cc = flat >> 6, dd = flat & 63;
                ldsT[dd * 65 + cc] = w[(h * 512 + ct * 64 + cc) * 64 + dd];   // coalesced in dd
            }
            __syncthreads();
#pragma unroll
            for (int i = 0; i < 16; i++) {
                int flat = i * 256 + tid, dd = flat >> 6, cc = flat & 63;
                int n = proj * 512 + h * 64 + dd;
                wqkvt[n * 512 + ct * 64 + cc] = f2b(ldsT[dd * 65 + cc]);      // coalesced in cc
            }
        } else {                                 // FF: 512x512 -> 512x512 transposed
            int b2 = blk - 192, rt = b2 >> 3, nt8 = b2 & 7;
#pragma unroll
            for (int i = 0; i < 16; i++) {
                int flat = i * 256 + tid, cc = flat >> 6, nn = flat & 63;
                ldsT[nn * 65 + cc] = wff[(rt * 64 + cc) * 512 + nt8 * 64 + nn];
            }
            __syncthreads();
#pragma unroll
            for (int i = 0; i < 16; i++) {
                int flat = i * 256 + tid, nn = flat >> 6, cc = flat & 63;
                wfft[(nt8 * 64 + nn) * 512 + rt * 64 + cc] = f2b(ldsT[nn * 65 + cc]);
            }
        }
    } else {                                     // LayerNorm1: one wave per token row
        int row  = (blk - 256) * 4 + (tid >> 6);
        int lane = tid & 63;
        const f32x4 a0 = *(const f32x4*)(x + row * Cdim + lane * 8);
        const f32x4 a1 = *(const f32x4*)(x + row * Cdim + lane * 8 + 4);
        float v[8] = {a0[0], a0[1], a0[2], a0[3], a1[0], a1[1], a1[2], a1[3]};
        float s = 0.f, sq = 0.f;
#pragma unroll
        for (int i = 0; i < 8; i++) { s += v[i]; sq += v[i] * v[i]; }
#pragma unroll
        for (int off = 1; off < 64; off <<= 1) { s += __shfl_xor(s, off); sq += __shfl_xor(sq, off); }
        float mean = s * (1.f / 512.f);
        float var  = sq * (1.f / 512.f) - mean * mean;
        float rstd = rsqrtf(var + 1e-5f);
        const f32x4 g0 = *(const f32x4*)(g + lane * 8);
        const f32x4 g1 = *(const f32x4*)(g + lane * 8 + 4);
        const f32x4 b0 = *(const f32x4*)(b + lane * 8);
        const f32x4 b1 = *(const f32x4*)(b + lane * 8 + 4);
        float gg[8] = {g0[0], g0[1], g0[2], g0[3], g1[0], g1[1], g1[2], g1[3]};
        float bb[8] = {b0[0], b0[1], b0[2], b0[3], b1[0], b1[1], b1[2], b1[3]};
        bf16x8 o;
#pragma unroll
        for (int i = 0; i < 8; i++) o[i] = f2b((v[i] - mean) * rstd * gg[i] + bb[i]);
        *(bf16x8*)(out + row * Cdim + lane * 8) = o;
    }
}

// ---------------- LayerNorm (standalone, for LN2): fp32 in, bf16 out ----------------
__global__ __launch_bounds__(256) void k_ln(const float* __restrict__ x, const float* __restrict__ g,
                                            const float* __restrict__ b, short* __restrict__ out) {
    int row  = blockIdx.x * 4 + (threadIdx.x >> 6);
    int lane = threadIdx.x & 63;
    const f32x4 a0 = *(const f32x4*)(x + row * Cdim + lane * 8);
    const f32x4 a1 = *(const f32x4*)(x + row * Cdim + lane * 8 + 4);
    float v[8] = {a0[0], a0[1], a0[2], a0[3], a1[0], a1[1], a1[2], a1[3]};
    float s = 0.f, sq = 0.f;
#pragma unroll
    for (int i = 0; i < 8; i++) { s += v[i]; sq += v[i] * v[i]; }
#pragma unroll
    for (int off = 1; off < 64; off <<= 1) { s += __shfl_xor(s, off); sq += __shfl_xor(sq, off); }
    float mean = s * (1.f / 512.f);
    float var  = sq * (1.f / 512.f) - mean * mean;
    float rstd = rsqrtf(var + 1e-5f);
    const f32x4 g0 = *(const f32x4*)(g + lane * 8);
    const f32x4 g1 = *(const f32x4*)(g + lane * 8 + 4);
    const f32x4 b0 = *(const f32x4*)(b + lane * 8);
    const f32x4 b1 = *(const f32x4*)(b + lane * 8 + 4);
    float gg[8] = {g0[0], g0[1], g0[2], g0[3], g1[0], g1[1], g1[2], g1[3]};
    float bb[8] = {b0[0], b0[1], b0[2], b0[3], b1[0], b1[1], b1[2], b1[3]};
    bf16x8 o;
#pragma unroll
    for (int i = 0; i < 8; i++) o[i] = f2b((v[i] - mean) * rstd * gg[i] + bb[i]);
    *(bf16x8*)(out + row * Cdim + lane * 8) = o;
}

// ---------------- QKV GEMM v2: 128x128 block tile, LDS-staged via global_load_lds ----------------
__global__ __launch_bounds__(256) void k_gemm_qkv(const short* __restrict__ A, const short* __restrict__ Wt,
                                                  short* __restrict__ q, short* __restrict__ k,
                                                  short* __restrict__ vt) {
    const int tid = threadIdx.x;
    const int wave = tid >> 6, lane = tid & 63;
    const int quad = lane >> 4, l15 = lane & 15;
    const int m0 = blockIdx.x * 128, n0 = blockIdx.y * 128;
    const int wm = wave & 1, wn = wave >> 1;
    __shared__ __align__(16) short As[128 * 32];   // [row][k] 64B rows
    __shared__ __align__(16) short Bs[128 * 32];
    f32x4 acc[4][4];
#pragma unroll
    for (int i = 0; i < 4; i++)
#pragma unroll
        for (int j = 0; j < 4; j++) acc[i][j] = (f32x4){0.f, 0.f, 0.f, 0.f};
    const int lr = lane >> 2, lc = lane & 3;       // staging: row = lane/4, 16B-col = lane%4
    const short* Ag = A  + (m0 + wave * 32 + lr) * Cdim + lc * 8;
    const short* Bg = Wt + (n0 + wave * 32 + lr) * Cdim + lc * 8;
    short* Al = As + wave * 1024;                  // wave-uniform LDS dest (shorts)
    short* Bl = Bs + wave * 1024;
    for (int kk = 0; kk < 16; kk++) {
        const int k0 = kk * 32;
        g2l16(Ag + k0,             Al);
        g2l16(Ag + 16 * Cdim + k0, Al + 512);
        g2l16(Bg + k0,             Bl);
        g2l16(Bg + 16 * Cdim + k0, Bl + 512);
        __syncthreads();                           // drains vmcnt before reads
        bf16x8 a[4], w[4];
#pragma unroll
        for (int mt = 0; mt < 4; mt++) a[mt] = *(const bf16x8*)(As + (wm * 64 + mt * 16 + l15) * 32 + quad * 8);
#pragma unroll
        for (int nt = 0; nt < 4; nt++) w[nt] = *(const bf16x8*)(Bs + (wn * 64 + nt * 16 + l15) * 32 + quad * 8);
#pragma unroll
        for (int mt = 0; mt < 4; mt++)
#pragma unroll
            for (int nt = 0; nt < 4; nt++)
                acc[mt][nt] = __builtin_amdgcn_mfma_f32_16x16x32_bf16(a[mt], w[nt], acc[mt][nt], 0, 0, 0);
        __syncthreads();                           // protect tiles before next staging
    }
    // epilogue: proj block-uniform (128 | 512), head wave-uniform (n0w 64-aligned)
    const int proj = n0 >> 9;
    const int n0w  = n0 + wn * 64;
    const int hh   = (n0w & 511) >> 6;
    const int m0w  = m0 + wm * 64;
#pragma unroll
    for (int mt = 0; mt < 4; mt++) {
#pragma unroll
        for (int r = 0; r < 4; r++) {
            int t  = m0w + mt * 16 + quad * 4 + r;
            int bi = t >> 11, tt = t & 2047;
#pragma unroll
            for (int nt = 0; nt < 4; nt++) {
                int d = nt * 16 + l15;
                short val = f2b(acc[mt][nt][r]);
                if (proj == 0)      q [((bi * Hn + hh) * Tseq + tt) * Dh + d] = val;
                else if (proj == 1) k [((bi * Hn + hh) * Tseq + tt) * Dh + d] = val;
                else                vt[((bi * Hn + hh) * Dh + d) * Tseq + tt] = val;
            }
        }
    }
}

// ---------------- causal flash attention v11: shared-LDS-tile restructure ----------------
// Round-12 post-mortem: FETCH 77->20.5MB (XCD affinity works) but dur -5% only; VGPR 96
// (compiler broke the register prefetch), occupancy 22%, per-wave-step residency ~9k cy vs
// ~1k cy issue -> latency-bound, too few independent chains, 4x redundant K/V loads.
// v11: 64 q-rows/block, one 16-row strip per wave, NO split-K, NO combine. All waves share
// one K-tile + one V-tile staged ONCE per block into LDS (global_load_lds, dbuf, 1 barrier
// per tile; staging latency hides under softmax). K/V LDS XOR-swizzled (rule #21: linear
// dest + pre-swizzled per-lane global src + swizzled ds_read) to kill the 16-way conflict.
// Per-CU balance exact: qg map {31-d, 16+d, 15-d, d} -> 66 tiles per CU; LPT order; bh->XCD
// affinity kept. LDS 41KB -> 3 blocks/CU = 12 waves; VGPR ~100 (launch_bounds(256,3)).
__global__ __launch_bounds__(256, 3) void k_attn(const short* __restrict__ qb, const short* __restrict__ kb,
                                                 const short* __restrict__ vtb, const float* __restrict__ x,
                                                 float* __restrict__ out1) {
    const int wave = threadIdx.x >> 6, lane = threadIdx.x & 63;
    const int quad = lane >> 4, l15 = lane & 15;
    const int D  = blockIdx.y * 32 + blockIdx.x;           // linear dispatch id
    const int j5 = D & 31;
    const int bh = (j5 & 7) * 4 + (j5 >> 3);               // XCD (D&7) -> bh group affinity
    const int u  = D >> 5, kq = u >> 3, d8 = u & 7;
    const int qg = (kq == 0) ? 31 - d8 : (kq == 1) ? 16 + d8 : (kq == 2) ? 15 - d8 : d8;
    const int q0  = qg * 64;                               // block's 64 q-rows
    const int qw0 = q0 + wave * 16;                        // this wave's 16 q-rows
    const int nkt = qg + 1;                                // 64-key tiles (keys <= q0+63)

    const short* Q = qb  + bh * Tseq * Dh;
    const short* K = kb  + bh * Tseq * Dh;
    const short* V = vtb + bh * Dh * Tseq;                 // [d][s]

    __shared__ __align__(16) short Ks[2][64 * 64];         // [key][d], XOR-swizzled cols
    __shared__ __align__(16) short Vs[2][64 * 64];         // [d][s],  XOR-swizzled cols
    __shared__ __align__(16) short Ps[4][16 * 72];         // per-wave P tile [q][s] stride 72
    short* pw = &Ps[wave][0];

    // staging geometry: call covers 8 rows x 128B; lane L -> row lr8, 16B slot lc8^lr8
    const int lr8 = lane >> 3, lc8 = lane & 7;
    const int sw8 = (lc8 ^ lr8) << 3;                      // pre-swizzled source col (shorts)
    const short* Ksrc = K + (wave * 16 + lr8) * Dh + sw8;  // wave stages K rows 16w..16w+15
    const short* Vsrc = V + (wave * 16 + lr8) * Tseq + sw8;// wave stages V d-rows 16w..16w+15

    // prologue: stage tile 0 into buf 0
    g2l16(Ksrc,            &Ks[0][wave * 1024]);
    g2l16(Ksrc + 8 * Dh,   &Ks[0][wave * 1024 + 512]);
    g2l16(Vsrc,            &Vs[0][wave * 1024]);
    g2l16(Vsrc + 8 * Tseq, &Vs[0][wave * 1024 + 512]);

    bf16x8 qa[2];
#pragma unroll
    for (int c = 0; c < 2; c++)
        qa[c] = *(const bf16x8*)(Q + (qw0 + l15) * Dh + c * 32 + quad * 8);

    f32x4 o[4];
#pragma unroll
    for (int i = 0; i < 4; i++) o[i] = (f32x4){0.f, 0.f, 0.f, 0.f};
    float m_i = NEG_BIG, l_i = 0.f;                        // per-lane: q-row = qw0 + l15

    const float sc = 0.125f * 1.44269504089f;              // scale * log2(e)
    const int sx = l15 & 7;                                // read-side swizzle (row&7)

    __syncthreads();                                       // tile 0 staged (drains vmcnt)

    for (int kt = 0; kt < nkt; kt++) {
        const short* Kb = &Ks[kt & 1][0];
        const short* Vb = &Vs[kt & 1][0];
        if (kt + 1 < nkt) {                                // stage next tile into other buf
            g2l16(Ksrc + (kt + 1) * 64 * Dh,            &Ks[(kt + 1) & 1][wave * 1024]);
            g2l16(Ksrc + (kt + 1) * 64 * Dh + 8 * Dh,   &Ks[(kt + 1) & 1][wave * 1024 + 512]);
            g2l16(Vsrc + (kt + 1) * 64,                 &Vs[(kt + 1) & 1][wave * 1024]);
            g2l16(Vsrc + (kt + 1) * 64 + 8 * Tseq,      &Vs[(kt + 1) & 1][wave * 1024 + 512]);
        }
        const int s0 = kt * 64;
        // ---- QK^T from LDS (swizzled reads) ----
        f32x4 st[4];
#pragma unroll
        for (int nt = 0; nt < 4; nt++) {
            bf16x8 k0 = *(const bf16x8*)(Kb + (nt * 16 + l15) * 64 + ((quad ^ sx) << 3));
            bf16x8 k1 = *(const bf16x8*)(Kb + (nt * 16 + l15) * 64 + (((4 | quad) ^ sx) << 3));
            f32x4 z = (f32x4){0.f, 0.f, 0.f, 0.f};
            z = __builtin_amdgcn_mfma_f32_16x16x32_bf16(k0, qa[0], z, 0, 0, 0);
            z = __builtin_amdgcn_mfma_f32_16x16x32_bf16(k1, qa[1], z, 0, 0, 0);
            st[nt] = z;
        }
        // ---- mask + scale (only the last tile crosses the diagonal for every wave) ----
        const int qq = qw0 + l15;
        if (kt == nkt - 1) {
#pragma unroll
            for (int nt = 0; nt < 4; nt++)
#pragma unroll
                for (int r = 0; r < 4; r++) {
                    int s = s0 + nt * 16 + quad * 4 + r;
                    st[nt][r] = (s > qq) ? NEG_BIG : st[nt][r] * sc;
                }
        } else {
#pragma unroll
            for (int nt = 0; nt < 4; nt++)
#pragma unroll
                for (int r = 0; r < 4; r++) st[nt][r] *= sc;
        }
        // ---- online softmax ----
        float mx = fmaxf(fmaxf(fmaxf(st[0][0], st[0][1]), fmaxf(st[0][2], st[0][3])),
                         fmaxf(fmaxf(st[1][0], st[1][1]), fmaxf(st[1][2], st[1][3])));
        mx = fmaxf(mx, fmaxf(fmaxf(fmaxf(st[2][0], st[2][1]), fmaxf(st[2][2], st[2][3])),
                             fmaxf(fmaxf(st[3][0], st[3][1]), fmaxf(st[3][2], st[3][3]))));
        mx = fmaxf(mx, __shfl_xor(mx, 16));
        mx = fmaxf(mx, __shfl_xor(mx, 32));
        float mn    = fmaxf(m_i, mx);
        float alpha = __builtin_amdgcn_exp2f(m_i - mn);
        m_i = mn;
        float rs = 0.f;
        bf16x4 pk[4];
#pragma unroll
        for (int nt = 0; nt < 4; nt++) {
#pragma unroll
            for (int r = 0; r < 4; r++) {
                float p = __builtin_amdgcn_exp2f(st[nt][r] - mn);   // masked -> 0
                rs += p;
                pk[nt][r] = f2b(p);
            }
        }
        rs += __shfl_xor(rs, 16);
        rs += __shfl_xor(rs, 32);
        l_i = l_i * alpha + rs;
#pragma unroll
        for (int nt = 0; nt < 4; nt++)
            *(bf16x4*)(pw + l15 * 72 + nt * 16 + quad * 4) = pk[nt];
#pragma unroll
        for (int r = 0; r < 4; r++) {
            float ar = __shfl(alpha, quad * 4 + r);
#pragma unroll
            for (int dt = 0; dt < 4; dt++) o[dt][r] *= ar;
        }
        asm volatile("s_waitcnt lgkmcnt(0)" ::: "memory");
        bf16x8 pa[2];
#pragma unroll
        for (int c = 0; c < 2; c++)
            pa[c] = *(const bf16x8*)(pw + l15 * 72 + c * 32 + quad * 8);
        // ---- PV from LDS V (swizzled reads) ----
#pragma unroll
        for (int c = 0; c < 2; c++)
#pragma unroll
            for (int v4 = 0; v4 < 4; v4++) {
                bf16x8 vb = *(const bf16x8*)(Vb + (v4 * 16 + l15) * 64 + ((((c << 2) | quad) ^ sx) << 3));
                o[v4] = __builtin_amdgcn_mfma_f32_16x16x32_bf16(pa[c], vb, o[v4], 0, 0, 0);
            }
        __syncthreads();    // waves done reading buf[kt&1]; staged tile kt+1 complete (vmcnt)
    }
    // ---- per-wave epilogue: rows qw0..qw0+15, no cross-wave combine ----
    const int bi = bh >> 3, hh = bh & 7;
#pragma unroll
    for (int r = 0; r < 4; r++) {
        int row = quad * 4 + r;
        float Lr  = __shfl(l_i, row);              // l_i uniform across the 4 quads per l15
        float inv = 1.f / Lr;
#pragma unroll
        for (int v4 = 0; v4 < 4; v4++) {
            int t   = qw0 + row;
            int idx = (bi * Tseq + t) * Cdim + hh * Dh + v4 * 16 + l15;
            out1[idx] = x[idx] + o[v4][r] * inv;
        }
    }
}

// ---------------- FF GEMM v2: 128x128 LDS-staged, fused bias+ReLU+residual, fp32 out ----------------
__global__ __launch_bounds__(256) void k_gemm_ff(const short* __restrict__ A, const short* __restrict__ Wt,
                                                 const float* __restrict__ bias, const float* __restrict__ res,
                                                 float* __restrict__ out) {
    const int tid = threadIdx.x;
    const int wave = tid >> 6, lane = tid & 63;
    const int quad = lane >> 4, l15 = lane & 15;
    const int m0 = blockIdx.x * 128, n0 = blockIdx.y * 128;
    const int wm = wave & 1, wn = wave >> 1;
    __shared__ __align__(16) short As[128 * 32];
    __shared__ __align__(16) short Bs[128 * 32];
    f32x4 acc[4][4];
#pragma unroll
    for (int i = 0; i < 4; i++)
#pragma unroll
        for (int j = 0; j < 4; j++) acc[i][j] = (f32x4){0.f, 0.f, 0.f, 0.f};
    const int lr = lane >> 2, lc = lane & 3;
    const short* Ag = A  + (m0 + wave * 32 + lr) * Cdim + lc * 8;
    const short* Bg = Wt + (n0 + wave * 32 + lr) * Cdim + lc * 8;
    short* Al = As + wave * 1024;
    short* Bl = Bs + wave * 1024;
    for (int kk = 0; kk < 16; kk++) {
        const int k0 = kk * 32;
        g2l16(Ag + k0,             Al);
        g2l16(Ag + 16 * Cdim + k0, Al + 512);
        g2l16(Bg + k0,             Bl);
        g2l16(Bg + 16 * Cdim + k0, Bl + 512);
        __syncthreads();
        bf16x8 a[4], w[4];
#pragma unroll
        for (int mt = 0; mt < 4; mt++) a[mt] = *(const bf16x8*)(As + (wm * 64 + mt * 16 + l15) * 32 + quad * 8);
#pragma unroll
        for (int nt = 0; nt < 4; nt++) w[nt] = *(const bf16x8*)(Bs + (wn * 64 + nt * 16 + l15) * 32 + quad * 8);
#pragma unroll
        for (int mt = 0; mt < 4; mt++)
#pragma unroll
            for (int nt = 0; nt < 4; nt++)
                acc[mt][nt] = __builtin_amdgcn_mfma_f32_16x16x32_bf16(a[mt], w[nt], acc[mt][nt], 0, 0, 0);
        __syncthreads();
    }
    const int m0w = m0 + wm * 64, n0w = n0 + wn * 64;
#pragma unroll
    for (int mt = 0; mt < 4; mt++) {
#pragma unroll
        for (int r = 0; r < 4; r++) {
            int t = m0w + mt * 16 + quad * 4 + r;
#pragma unroll
            for (int nt = 0; nt < 4; nt++) {
                int n = n0w + nt * 16 + l15;
                float fv = acc[mt][nt][r] + bias[n];
                fv = fmaxf(fv, 0.f);
                out[t * Cdim + n] = res[t * Cdim + n] + fv;
            }
        }
    }
}

extern "C" void kernel_launch(void* const* d_in, const int* in_sizes, int n_in,
                              void* d_out, int out_size, void* d_ws, size_t ws_size,
                              hipStream_t stream) {
    const float* x   = (const float*)d_in[0];
    const float* wq  = (const float*)d_in[1];
    const float* wk  = (const float*)d_in[2];
    const float* wv  = (const float*)d_in[3];
    const float* wff = (const float*)d_in[4];
    const float* bff = (const float*)d_in[5];
    const float* g1  = (const float*)d_in[6];
    const float* b1  = (const float*)d_in[7];
    const float* g2  = (const float*)d_in[8];
    const float* b2  = (const float*)d_in[9];

    char* p = (char*)d_ws;                                  // ~50 MB total scratch
    short* wqkvt = (short*)p; p += (size_t)NQKV * Cdim * 2;
    short* wfft  = (short*)p; p += (size_t)Cdim * Cdim * 2;
    short* h1    = (short*)p; p += (size_t)BT * Cdim * 2;   // reused as h2 after attention
    short* qb    = (short*)p; p += (size_t)BT * Cdim * 2;
    short* kb    = (short*)p; p += (size_t)BT * Cdim * 2;
    short* vtb   = (short*)p; p += (size_t)BT * Cdim * 2;
    float* out1  = (float*)p; p += (size_t)BT * Cdim * 4;

    hipLaunchKernelGGL(k_prep,     dim3(2304),    dim3(256), 0, stream,
                       wq, wk, wv, wff, wqkvt, wfft, x, g1, b1, h1);
    hipLaunchKernelGGL(k_gemm_qkv, dim3(64, 12),  dim3(256), 0, stream, h1, wqkvt, qb, kb, vtb);
    hipLaunchKernelGGL(k_attn,     dim3(32, 32),  dim3(256), 0, stream, qb, kb, vtb, x, out1);
    hipLaunchKernelGGL(k_ln,       dim3(2048),    dim3(256), 0, stream, out1, g2, b2, h1);
    hipLaunchKernelGGL(k_gemm_ff,  dim3(64, 4),   dim3(256), 0, stream, h1, wfft, bff, out1, (float*)d_out);
}

// Round 3
// 172.900 us; speedup vs baseline: 1.6222x; 1.0450x over previous
//
#include <hip/hip_runtime.h>

#define Bsz  4
#define Tseq 2048
#define Cdim 512
#define Hn   8
#define Dh   64
#define BT   8192     // Bsz*Tseq tokens
#define NQKV 1536
#define NEG_BIG (-1e30f)

typedef __attribute__((ext_vector_type(8))) short bf16x8;  // 8 bf16 = 4 VGPRs
typedef __attribute__((ext_vector_type(4))) short bf16x4;  // 4 bf16 = 2 VGPRs
typedef __attribute__((ext_vector_type(4))) float f32x4;

__device__ __forceinline__ float b2f(short s) {
    unsigned u = ((unsigned)(unsigned short)s) << 16;
    float f; __builtin_memcpy(&f, &u, 4); return f;
}
__device__ __forceinline__ short f2b(float f) {
    unsigned u; __builtin_memcpy(&u, &f, 4);
    u = (u + 0x7fffu + ((u >> 16) & 1u)) >> 16;   // RNE
    return (short)u;
}
// async global->LDS, 16B/lane; LDS dest = wave-uniform base + lane*16
__device__ __forceinline__ void g2l16(const short* g, short* l) {
    __builtin_amdgcn_global_load_lds(
        (const __attribute__((address_space(1))) unsigned int*)(uintptr_t)g,
        (__attribute__((address_space(3))) unsigned int*)l, 16, 0, 0);
}

// ---------------- prep: fused weight transpose (blocks 0..255) + LayerNorm1 (blocks 256..2303) ----------------
__global__ __launch_bounds__(256) void k_prep(const float* __restrict__ wq, const float* __restrict__ wk,
                                              const float* __restrict__ wv, const float* __restrict__ wff,
                                              short* __restrict__ wqkvt, short* __restrict__ wfft,
                                              const float* __restrict__ x, const float* __restrict__ g,
                                              const float* __restrict__ b, short* __restrict__ out) {
    const int blk = blockIdx.x, tid = threadIdx.x;
    if (blk < 256) {
        __shared__ float ldsT[64 * 65];          // 64x64 tile, pad 65: conflict-free both phases
        if (blk < 192) {                         // QKV heads: per-head 512x64 -> 64x512
            int hm = blk >> 3, ct = blk & 7;
            int proj = hm >> 3, h = hm & 7;
            const float* w = (proj == 0) ? wq : (proj == 1 ? wk : wv);
#pragma unroll
            for (int i = 0; i < 16; i++) {
                int flat = i * 256 + tid, cc = flat >> 6, dd = flat & 63;
                ldsT[dd * 65 + cc] = w[(h * 512 + ct * 64 + cc) * 64 + dd];   // coalesced in dd
            }
            __syncthreads();
#pragma unroll
            for (int i = 0; i < 16; i++) {
                int flat = i * 256 + tid, dd = flat >> 6, cc = flat & 63;
                int n = proj * 512 + h * 64 + dd;
                wqkvt[n * 512 + ct * 64 + cc] = f2b(ldsT[dd * 65 + cc]);      // coalesced in cc
            }
        } else {                                 // FF: 512x512 -> 512x512 transposed
            int b2 = blk - 192, rt = b2 >> 3, nt8 = b2 & 7;
#pragma unroll
            for (int i = 0; i < 16; i++) {
                int flat = i * 256 + tid, cc = flat >> 6, nn = flat & 63;
                ldsT[nn * 65 + cc] = wff[(rt * 64 + cc) * 512 + nt8 * 64 + nn];
            }
            __syncthreads();
#pragma unroll
            for (int i = 0; i < 16; i++) {
                int flat = i * 256 + tid, nn = flat >> 6, cc = flat & 63;
                wfft[(nt8 * 64 + nn) * 512 + rt * 64 + cc] = f2b(ldsT[nn * 65 + cc]);
            }
        }
    } else {                                     // LayerNorm1: one wave per token row
        int row  = (blk - 256) * 4 + (tid >> 6);
        int lane = tid & 63;
        const f32x4 a0 = *(const f32x4*)(x + row * Cdim + lane * 8);
        const f32x4 a1 = *(const f32x4*)(x + row * Cdim + lane * 8 + 4);
        float v[8] = {a0[0], a0[1], a0[2], a0[3], a1[0], a1[1], a1[2], a1[3]};
        float s = 0.f, sq = 0.f;
#pragma unroll
        for (int i = 0; i < 8; i++) { s += v[i]; sq += v[i] * v[i]; }
#pragma unroll
        for (int off = 1; off < 64; off <<= 1) { s += __shfl_xor(s, off); sq += __shfl_xor(sq, off); }
        float mean = s * (1.f / 512.f);
        float var  = sq * (1.f / 512.f) - mean * mean;
        float rstd = rsqrtf(var + 1e-5f);
        const f32x4 g0 = *(const f32x4*)(g + lane * 8);
        const f32x4 g1 = *(const f32x4*)(g + lane * 8 + 4);
        const f32x4 b0 = *(const f32x4*)(b + lane * 8);
        const f32x4 b1 = *(const f32x4*)(b + lane * 8 + 4);
        float gg[8] = {g0[0], g0[1], g0[2], g0[3], g1[0], g1[1], g1[2], g1[3]};
        float bb[8] = {b0[0], b0[1], b0[2], b0[3], b1[0], b1[1], b1[2], b1[3]};
        bf16x8 o;
#pragma unroll
        for (int i = 0; i < 8; i++) o[i] = f2b((v[i] - mean) * rstd * gg[i] + bb[i]);
        *(bf16x8*)(out + row * Cdim + lane * 8) = o;
    }
}

// ---------------- LayerNorm (standalone, for LN2): fp32 in, bf16 out ----------------
__global__ __launch_bounds__(256) void k_ln(const float* __restrict__ x, const float* __restrict__ g,
                                            const float* __restrict__ b, short* __restrict__ out) {
    int row  = blockIdx.x * 4 + (threadIdx.x >> 6);
    int lane = threadIdx.x & 63;
    const f32x4 a0 = *(const f32x4*)(x + row * Cdim + lane * 8);
    const f32x4 a1 = *(const f32x4*)(x + row * Cdim + lane * 8 + 4);
    float v[8] = {a0[0], a0[1], a0[2], a0[3], a1[0], a1[1], a1[2], a1[3]};
    float s = 0.f, sq = 0.f;
#pragma unroll
    for (int i = 0; i < 8; i++) { s += v[i]; sq += v[i] * v[i]; }
#pragma unroll
    for (int off = 1; off < 64; off <<= 1) { s += __shfl_xor(s, off); sq += __shfl_xor(sq, off); }
    float mean = s * (1.f / 512.f);
    float var  = sq * (1.f / 512.f) - mean * mean;
    float rstd = rsqrtf(var + 1e-5f);
    const f32x4 g0 = *(const f32x4*)(g + lane * 8);
    const f32x4 g1 = *(const f32x4*)(g + lane * 8 + 4);
    const f32x4 b0 = *(const f32x4*)(b + lane * 8);
    const f32x4 b1 = *(const f32x4*)(b + lane * 8 + 4);
    float gg[8] = {g0[0], g0[1], g0[2], g0[3], g1[0], g1[1], g1[2], g1[3]};
    float bb[8] = {b0[0], b0[1], b0[2], b0[3], b1[0], b1[1], b1[2], b1[3]};
    bf16x8 o;
#pragma unroll
    for (int i = 0; i < 8; i++) o[i] = f2b((v[i] - mean) * rstd * gg[i] + bb[i]);
    *(bf16x8*)(out + row * Cdim + lane * 8) = o;
}

// ---------------- QKV GEMM v3: 128x128, 2-phase double-buffered LDS pipeline ----------------
// Round-13: v2 was 1-phase (stage -> drain -> compute), 16 serial latency exposures,
// Mfma 8% / occ 15%. v3 stages step k+1 BEFORE computing step k (T3 minimum-2-phase,
// one barrier/step): the barrier's vmcnt drain now waits on loads that aged a full
// compute phase. LDS 32KB (2x(As+Bs)).
__global__ __launch_bounds__(256) void k_gemm_qkv(const short* __restrict__ A, const short* __restrict__ Wt,
                                                  short* __restrict__ q, short* __restrict__ k,
                                                  short* __restrict__ vt) {
    const int tid = threadIdx.x;
    const int wave = tid >> 6, lane = tid & 63;
    const int quad = lane >> 4, l15 = lane & 15;
    const int m0 = blockIdx.x * 128, n0 = blockIdx.y * 128;
    const int wm = wave & 1, wn = wave >> 1;
    __shared__ __align__(16) short As[2][128 * 32];   // [buf][row][k] 64B rows
    __shared__ __align__(16) short Bs[2][128 * 32];
    f32x4 acc[4][4];
#pragma unroll
    for (int i = 0; i < 4; i++)
#pragma unroll
        for (int j = 0; j < 4; j++) acc[i][j] = (f32x4){0.f, 0.f, 0.f, 0.f};
    const int lr = lane >> 2, lc = lane & 3;       // staging: row = lane/4, 16B-col = lane%4
    const short* Ag = A  + (m0 + wave * 32 + lr) * Cdim + lc * 8;
    const short* Bg = Wt + (n0 + wave * 32 + lr) * Cdim + lc * 8;
    // prologue: stage K-step 0 into buf 0
    g2l16(Ag,             &As[0][wave * 1024]);
    g2l16(Ag + 16 * Cdim, &As[0][wave * 1024 + 512]);
    g2l16(Bg,             &Bs[0][wave * 1024]);
    g2l16(Bg + 16 * Cdim, &Bs[0][wave * 1024 + 512]);
    __syncthreads();
    for (int kk = 0; kk < 16; kk++) {
        const int cur = kk & 1, nxt = cur ^ 1;
        if (kk + 1 < 16) {                         // issue next-step staging BEFORE compute
            const int k0 = (kk + 1) * 32;
            g2l16(Ag + k0,             &As[nxt][wave * 1024]);
            g2l16(Ag + 16 * Cdim + k0, &As[nxt][wave * 1024 + 512]);
            g2l16(Bg + k0,             &Bs[nxt][wave * 1024]);
            g2l16(Bg + 16 * Cdim + k0, &Bs[nxt][wave * 1024 + 512]);
        }
        bf16x8 a[4], w[4];
#pragma unroll
        for (int mt = 0; mt < 4; mt++) a[mt] = *(const bf16x8*)(&As[cur][(wm * 64 + mt * 16 + l15) * 32 + quad * 8]);
#pragma unroll
        for (int nt = 0; nt < 4; nt++) w[nt] = *(const bf16x8*)(&Bs[cur][(wn * 64 + nt * 16 + l15) * 32 + quad * 8]);
#pragma unroll
        for (int mt = 0; mt < 4; mt++)
#pragma unroll
            for (int nt = 0; nt < 4; nt++)
                acc[mt][nt] = __builtin_amdgcn_mfma_f32_16x16x32_bf16(a[mt], w[nt], acc[mt][nt], 0, 0, 0);
        __syncthreads();                           // reads of cur done; staged nxt complete
    }
    // epilogue: proj block-uniform (128 | 512), head wave-uniform (n0w 64-aligned)
    const int proj = n0 >> 9;
    const int n0w  = n0 + wn * 64;
    const int hh   = (n0w & 511) >> 6;
    const int m0w  = m0 + wm * 64;
#pragma unroll
    for (int mt = 0; mt < 4; mt++) {
#pragma unroll
        for (int r = 0; r < 4; r++) {
            int t  = m0w + mt * 16 + quad * 4 + r;
            int bi = t >> 11, tt = t & 2047;
#pragma unroll
            for (int nt = 0; nt < 4; nt++) {
                int d = nt * 16 + l15;
                short val = f2b(acc[mt][nt][r]);
                if (proj == 0)      q [((bi * Hn + hh) * Tseq + tt) * Dh + d] = val;
                else if (proj == 1) k [((bi * Hn + hh) * Tseq + tt) * Dh + d] = val;
                else                vt[((bi * Hn + hh) * Dh + d) * Tseq + tt] = val;
            }
        }
    }
}

// ---------------- causal flash attention v11: shared-LDS-tile restructure ----------------
__global__ __launch_bounds__(256, 3) void k_attn(const short* __restrict__ qb, const short* __restrict__ kb,
                                                 const short* __restrict__ vtb, const float* __restrict__ x,
                                                 float* __restrict__ out1) {
    const int wave = threadIdx.x >> 6, lane = threadIdx.x & 63;
    const int quad = lane >> 4, l15 = lane & 15;
    const int D  = blockIdx.y * 32 + blockIdx.x;           // linear dispatch id
    const int j5 = D & 31;
    const int bh = (j5 & 7) * 4 + (j5 >> 3);               // XCD (D&7) -> bh group affinity
    const int u  = D >> 5, kq = u >> 3, d8 = u & 7;
    const int qg = (kq == 0) ? 31 - d8 : (kq == 1) ? 16 + d8 : (kq == 2) ? 15 - d8 : d8;
    const int q0  = qg * 64;                               // block's 64 q-rows
    const int qw0 = q0 + wave * 16;                        // this wave's 16 q-rows
    const int nkt = qg + 1;                                // 64-key tiles (keys <= q0+63)

    const short* Q = qb  + bh * Tseq * Dh;
    const short* K = kb  + bh * Tseq * Dh;
    const short* V = vtb + bh * Dh * Tseq;                 // [d][s]

    __shared__ __align__(16) short Ks[2][64 * 64];         // [key][d], XOR-swizzled cols
    __shared__ __align__(16) short Vs[2][64 * 64];         // [d][s],  XOR-swizzled cols
    __shared__ __align__(16) short Ps[4][16 * 72];         // per-wave P tile [q][s] stride 72
    short* pw = &Ps[wave][0];

    // staging geometry: call covers 8 rows x 128B; lane L -> row lr8, 16B slot lc8^lr8
    const int lr8 = lane >> 3, lc8 = lane & 7;
    const int sw8 = (lc8 ^ lr8) << 3;                      // pre-swizzled source col (shorts)
    const short* Ksrc = K + (wave * 16 + lr8) * Dh + sw8;  // wave stages K rows 16w..16w+15
    const short* Vsrc = V + (wave * 16 + lr8) * Tseq + sw8;// wave stages V d-rows 16w..16w+15

    // prologue: stage tile 0 into buf 0
    g2l16(Ksrc,            &Ks[0][wave * 1024]);
    g2l16(Ksrc + 8 * Dh,   &Ks[0][wave * 1024 + 512]);
    g2l16(Vsrc,            &Vs[0][wave * 1024]);
    g2l16(Vsrc + 8 * Tseq, &Vs[0][wave * 1024 + 512]);

    bf16x8 qa[2];
#pragma unroll
    for (int c = 0; c < 2; c++)
        qa[c] = *(const bf16x8*)(Q + (qw0 + l15) * Dh + c * 32 + quad * 8);

    f32x4 o[4];
#pragma unroll
    for (int i = 0; i < 4; i++) o[i] = (f32x4){0.f, 0.f, 0.f, 0.f};
    float m_i = NEG_BIG, l_i = 0.f;                        // per-lane: q-row = qw0 + l15

    const float sc = 0.125f * 1.44269504089f;              // scale * log2(e)
    const int sx = l15 & 7;                                // read-side swizzle (row&7)

    __syncthreads();                                       // tile 0 staged (drains vmcnt)

    for (int kt = 0; kt < nkt; kt++) {
        const short* Kb = &Ks[kt & 1][0];
        const short* Vb = &Vs[kt & 1][0];
        if (kt + 1 < nkt) {                                // stage next tile into other buf
            g2l16(Ksrc + (kt + 1) * 64 * Dh,            &Ks[(kt + 1) & 1][wave * 1024]);
            g2l16(Ksrc + (kt + 1) * 64 * Dh + 8 * Dh,   &Ks[(kt + 1) & 1][wave * 1024 + 512]);
            g2l16(Vsrc + (kt + 1) * 64,                 &Vs[(kt + 1) & 1][wave * 1024]);
            g2l16(Vsrc + (kt + 1) * 64 + 8 * Tseq,      &Vs[(kt + 1) & 1][wave * 1024 + 512]);
        }
        const int s0 = kt * 64;
        // ---- QK^T from LDS (swizzled reads) ----
        f32x4 st[4];
#pragma unroll
        for (int nt = 0; nt < 4; nt++) {
            bf16x8 k0 = *(const bf16x8*)(Kb + (nt * 16 + l15) * 64 + ((quad ^ sx) << 3));
            bf16x8 k1 = *(const bf16x8*)(Kb + (nt * 16 + l15) * 64 + (((4 | quad) ^ sx) << 3));
            f32x4 z = (f32x4){0.f, 0.f, 0.f, 0.f};
            z = __builtin_amdgcn_mfma_f32_16x16x32_bf16(k0, qa[0], z, 0, 0, 0);
            z = __builtin_amdgcn_mfma_f32_16x16x32_bf16(k1, qa[1], z, 0, 0, 0);
            st[nt] = z;
        }
        // ---- mask + scale (only the last tile crosses the diagonal for every wave) ----
        const int qq = qw0 + l15;
        if (kt == nkt - 1) {
#pragma unroll
            for (int nt = 0; nt < 4; nt++)
#pragma unroll
                for (int r = 0; r < 4; r++) {
                    int s = s0 + nt * 16 + quad * 4 + r;
                    st[nt][r] = (s > qq) ? NEG_BIG : st[nt][r] * sc;
                }
        } else {
#pragma unroll
            for (int nt = 0; nt < 4; nt++)
#pragma unroll
                for (int r = 0; r < 4; r++) st[nt][r] *= sc;
        }
        // ---- online softmax ----
        float mx = fmaxf(fmaxf(fmaxf(st[0][0], st[0][1]), fmaxf(st[0][2], st[0][3])),
                         fmaxf(fmaxf(st[1][0], st[1][1]), fmaxf(st[1][2], st[1][3])));
        mx = fmaxf(mx, fmaxf(fmaxf(fmaxf(st[2][0], st[2][1]), fmaxf(st[2][2], st[2][3])),
                             fmaxf(fmaxf(st[3][0], st[3][1]), fmaxf(st[3][2], st[3][3]))));
        mx = fmaxf(mx, __shfl_xor(mx, 16));
        mx = fmaxf(mx, __shfl_xor(mx, 32));
        float mn    = fmaxf(m_i, mx);
        float alpha = __builtin_amdgcn_exp2f(m_i - mn);
        m_i = mn;
        float rs = 0.f;
        bf16x4 pk[4];
#pragma unroll
        for (int nt = 0; nt < 4; nt++) {
#pragma unroll
            for (int r = 0; r < 4; r++) {
                float p = __builtin_amdgcn_exp2f(st[nt][r] - mn);   // masked -> 0
                rs += p;
                pk[nt][r] = f2b(p);
            }
        }
        rs += __shfl_xor(rs, 16);
        rs += __shfl_xor(rs, 32);
        l_i = l_i * alpha + rs;
#pragma unroll
        for (int nt = 0; nt < 4; nt++)
            *(bf16x4*)(pw + l15 * 72 + nt * 16 + quad * 4) = pk[nt];
#pragma unroll
        for (int r = 0; r < 4; r++) {
            float ar = __shfl(alpha, quad * 4 + r);
#pragma unroll
            for (int dt = 0; dt < 4; dt++) o[dt][r] *= ar;
        }
        asm volatile("s_waitcnt lgkmcnt(0)" ::: "memory");
        bf16x8 pa[2];
#pragma unroll
        for (int c = 0; c < 2; c++)
            pa[c] = *(const bf16x8*)(pw + l15 * 72 + c * 32 + quad * 8);
        // ---- PV from LDS V (swizzled reads) ----
#pragma unroll
        for (int c = 0; c < 2; c++)
#pragma unroll
            for (int v4 = 0; v4 < 4; v4++) {
                bf16x8 vb = *(const bf16x8*)(Vb + (v4 * 16 + l15) * 64 + ((((c << 2) | quad) ^ sx) << 3));
                o[v4] = __builtin_amdgcn_mfma_f32_16x16x32_bf16(pa[c], vb, o[v4], 0, 0, 0);
            }
        __syncthreads();    // waves done reading buf[kt&1]; staged tile kt+1 complete (vmcnt)
    }
    // ---- per-wave epilogue: rows qw0..qw0+15, no cross-wave combine ----
    const int bi = bh >> 3, hh = bh & 7;
#pragma unroll
    for (int r = 0; r < 4; r++) {
        int row = quad * 4 + r;
        float Lr  = __shfl(l_i, row);              // l_i uniform across the 4 quads per l15
        float inv = 1.f / Lr;
#pragma unroll
        for (int v4 = 0; v4 < 4; v4++) {
            int t   = qw0 + row;
            int idx = (bi * Tseq + t) * Cdim + hh * Dh + v4 * 16 + l15;
            out1[idx] = x[idx] + o[v4][r] * inv;
        }
    }
}

// ---------------- FF GEMM v3: 128x64 tile, 2-phase double-buffered, fused bias+ReLU+residual ----------------
// Round-13: v2 was 256 blocks = 1 block/CU = 1 wave/SIMD -> barrier drains had zero overlap.
// v3: 128x64 tile -> 512 blocks (2/CU) + 2-phase staging pipeline as in k_gemm_qkv.
__global__ __launch_bounds__(256) void k_gemm_ff(const short* __restrict__ A, const short* __restrict__ Wt,
                                                 const float* __restrict__ bias, const float* __restrict__ res,
                                                 float* __restrict__ out) {
    const int tid = threadIdx.x;
    const int wave = tid >> 6, lane = tid & 63;
    const int quad = lane >> 4, l15 = lane & 15;
    const int m0 = blockIdx.x * 128, n0 = blockIdx.y * 64;
    const int wm = wave & 1, wn = wave >> 1;           // wave -> 64-row half, 32-col half
    __shared__ __align__(16) short As[2][128 * 32];    // 8 KB per buf
    __shared__ __align__(16) short Bs[2][64 * 32];     // 4 KB per buf
    f32x4 acc[4][2];
#pragma unroll
    for (int i = 0; i < 4; i++)
#pragma unroll
        for (int j = 0; j < 2; j++) acc[i][j] = (f32x4){0.f, 0.f, 0.f, 0.f};
    const int lr = lane >> 2, lc = lane & 3;           // 16 rows x 4 slots per g2l16 call
    const short* Ag = A  + (m0 + wave * 32 + lr) * Cdim + lc * 8;
    const short* Bg = Wt + (n0 + wave * 16 + lr) * Cdim + lc * 8;
    // prologue: stage K-step 0 into buf 0
    g2l16(Ag,             &As[0][wave * 1024]);
    g2l16(Ag + 16 * Cdim, &As[0][wave * 1024 + 512]);
    g2l16(Bg,             &Bs[0][wave * 512]);
    __syncthreads();
    for (int kk = 0; kk < 16; kk++) {
        const int cur = kk & 1, nxt = cur ^ 1;
        if (kk + 1 < 16) {
            const int k0 = (kk + 1) * 32;
            g2l16(Ag + k0,             &As[nxt][wave * 1024]);
            g2l16(Ag + 16 * Cdim + k0, &As[nxt][wave * 1024 + 512]);
            g2l16(Bg + k0,             &Bs[nxt][wave * 512]);
        }
        bf16x8 a[4], w[2];
#pragma unroll
        for (int mt = 0; mt < 4; mt++) a[mt] = *(const bf16x8*)(&As[cur][(wm * 64 + mt * 16 + l15) * 32 + quad * 8]);
#pragma unroll
        for (int nt = 0; nt < 2; nt++) w[nt] = *(const bf16x8*)(&Bs[cur][(wn * 32 + nt * 16 + l15) * 32 + quad * 8]);
#pragma unroll
        for (int mt = 0; mt < 4; mt++)
#pragma unroll
            for (int nt = 0; nt < 2; nt++)
                acc[mt][nt] = __builtin_amdgcn_mfma_f32_16x16x32_bf16(a[mt], w[nt], acc[mt][nt], 0, 0, 0);
        __syncthreads();
    }
    const int m0w = m0 + wm * 64, n0w = n0 + wn * 32;
#pragma unroll
    for (int mt = 0; mt < 4; mt++) {
#pragma unroll
        for (int r = 0; r < 4; r++) {
            int t = m0w + mt * 16 + quad * 4 + r;
#pragma unroll
            for (int nt = 0; nt < 2; nt++) {
                int n = n0w + nt * 16 + l15;
                float fv = acc[mt][nt][r] + bias[n];
                fv = fmaxf(fv, 0.f);
                out[t * Cdim + n] = res[t * Cdim + n] + fv;
            }
        }
    }
}

extern "C" void kernel_launch(void* const* d_in, const int* in_sizes, int n_in,
                              void* d_out, int out_size, void* d_ws, size_t ws_size,
                              hipStream_t stream) {
    const float* x   = (const float*)d_in[0];
    const float* wq  = (const float*)d_in[1];
    const float* wk  = (const float*)d_in[2];
    const float* wv  = (const float*)d_in[3];
    const float* wff = (const float*)d_in[4];
    const float* bff = (const float*)d_in[5];
    const float* g1  = (const float*)d_in[6];
    const float* b1  = (const float*)d_in[7];
    const float* g2  = (const float*)d_in[8];
    const float* b2  = (const float*)d_in[9];

    char* p = (char*)d_ws;                                  // ~50 MB total scratch
    short* wqkvt = (short*)p; p += (size_t)NQKV * Cdim * 2;
    short* wfft  = (short*)p; p += (size_t)Cdim * Cdim * 2;
    short* h1    = (short*)p; p += (size_t)BT * Cdim * 2;   // reused as h2 after attention
    short* qb    = (short*)p; p += (size_t)BT * Cdim * 2;
    short* kb    = (short*)p; p += (size_t)BT * Cdim * 2;
    short* vtb   = (short*)p; p += (size_t)BT * Cdim * 2;
    float* out1  = (float*)p; p += (size_t)BT * Cdim * 4;

    hipLaunchKernelGGL(k_prep,     dim3(2304),    dim3(256), 0, stream,
                       wq, wk, wv, wff, wqkvt, wfft, x, g1, b1, h1);
    hipLaunchKernelGGL(k_gemm_qkv, dim3(64, 12),  dim3(256), 0, stream, h1, wqkvt, qb, kb, vtb);
    hipLaunchKernelGGL(k_attn,     dim3(32, 32),  dim3(256), 0, stream, qb, kb, vtb, x, out1);
    hipLaunchKernelGGL(k_ln,       dim3(2048),    dim3(256), 0, stream, out1, g2, b2, h1);
    hipLaunchKernelGGL(k_gemm_ff,  dim3(64, 8),   dim3(256), 0, stream, h1, wfft, bff, out1, (float*)d_out);
}